// Round 4
// baseline (130.781 us; speedup 1.0000x reference)
//
#include <hip/hip_runtime.h>

#define SEQ 4096
#define DIM 1024
#define MD 64
#define TOPK 16
#define WPB 4        // waves per block
#define RPW 4        // rows per wave, processed SEQUENTIALLY (software pipeline)

// One wave pipelines RPW rows: while row r's serial chain (gather -> Hadamard
// -> top-k ballot search -> Hadamard -> bpermute) runs, row r+1's x-loads are
// already in flight. Epilogue uses out = x + signs*w[bin] (signs^2 == 1), so x
// stays in registers and phase-4 LDS readback is eliminated.
// Identities (validated R1-R3):
//   z_m = 1024^-0.5 * H64(s)_m,  s[m] = sum_k (x*signs)[perm[m+64k]]
//   out[d] = x[d] + signs[d] * (1024^-0.5 * H64(zs))[inv_perm[d] & 63]
__global__ __launch_bounds__(WPB * 64) void csa_kernel(
    const float* __restrict__ x,
    const float* __restrict__ gates,
    const float* __restrict__ alpha,
    const float* __restrict__ tau,
    const float* __restrict__ signs,
    const int*   __restrict__ perm,
    const int*   __restrict__ inv_perm,
    const int*   __restrict__ target_idx,
    float*       __restrict__ out)
{
    __shared__ float y[WPB][DIM];                     // 16 KB/block

    const int lane = threadIdx.x & 63;
    const int wv   = threadIdx.x >> 6;
    const int base = (blockIdx.x * WPB + wv) * RPW;   // first of RPW rows
    const int b    = base >> 12;                      // SEQ=4096; all RPW rows share b

    const float4* x4  = (const float4*)x;
    const float4* sg4 = (const float4*)signs;
    const int4*   ip4 = (const int4*)inv_perm;

    // Per-batch scalars + gather indices, hoisted across all RPW rows.
    const int   ti   = target_idx[0];                 // NT == 1
    const float gate = gates[(b + ti) * MD + lane];
    const float tauv = fabsf(tau[b + ti]);
    const float al   = alpha[b + ti];
    int pidx[16];
    #pragma unroll
    for (int k = 0; k < 16; ++k) pidx[k] = perm[lane + 64 * k];

    // Prologue: load row 0 into registers.
    float4 xv[4];
    #pragma unroll
    for (int c = 0; c < 4; ++c)
        xv[c] = x4[(size_t)base * (DIM / 4) + c * 64 + lane];

    #pragma unroll
    for (int r = 0; r < RPW; ++r) {
        // ---- Phase 1: stage y = x*signs into this wave's LDS row
        #pragma unroll
        for (int c = 0; c < 4; ++c) {
            const float4 sg = sg4[c * 64 + lane];
            float4 yv;
            yv.x = xv[c].x * sg.x; yv.y = xv[c].y * sg.y;
            yv.z = xv[c].z * sg.z; yv.w = xv[c].w * sg.w;
            ((float4*)y[wv])[c * 64 + lane] = yv;
        }

        // ---- Prefetch next row's x (overlaps the whole compute chain below)
        float4 xn[4];
        if (r + 1 < RPW) {
            #pragma unroll
            for (int c = 0; c < 4; ++c)
                xn[c] = x4[(size_t)(base + r + 1) * (DIM / 4) + c * 64 + lane];
        }

        // ---- Phase 2: fold 1024 -> 64 bins (lane m owns bin m)
        float s = 0.f;
        #pragma unroll
        for (int k = 0; k < 16; ++k) s += y[wv][pidx[k]];

        // ---- Phase 3a: 64-pt Hadamard (shuffle-xor butterflies)
        float v = s;
        #pragma unroll
        for (int bit = 1; bit < MD; bit <<= 1) {
            const float o = __shfl_xor(v, bit, 64);
            v = (lane & bit) ? (o - v) : (v + o);
        }
        const float g  = gate * v * 0.03125f;          // 1024^-0.5
        const float ag = fabsf(g);

        // ---- Phase 3b: exact top-16 via bitwise binary search on |g| bits;
        // ties -> lowest lane (matches jax.lax.top_k).
        const unsigned ka = __float_as_uint(ag);
        unsigned T = 0u;
        #pragma unroll
        for (int bit = 30; bit >= 0; --bit) {
            const unsigned cand = T | (1u << bit);
            if (__popcll(__ballot(ka >= cand)) >= TOPK) T = cand;
        }
        const int ngt = __popcll(__ballot(ka > T));
        const int erk = __popcll(__ballot(ka == T) & ((1ull << lane) - 1ull));
        const bool keep = (ka > T) || ((ka == T) && (erk < TOPK - ngt));

        float zs = (keep && ag >= tauv) ? al * g : 0.f;

        // ---- Phase 3c: second 64-pt Hadamard
        #pragma unroll
        for (int bit = 1; bit < MD; bit <<= 1) {
            const float o = __shfl_xor(zs, bit, 64);
            zs = (lane & bit) ? (o - zs) : (zs + o);
        }
        const int wb = __float_as_int(zs * 0.03125f);  // 1024^-0.5

        // ---- Phase 4: out = x + signs * w[inv_perm & 63]  (x from registers)
        float* outr = out + (size_t)(base + r) * DIM;
        #pragma unroll
        for (int c = 0; c < 4; ++c) {
            const float4 sg = sg4[c * 64 + lane];
            const int4   ip = ip4[c * 64 + lane];
            float4 o;
            o.x = xv[c].x + sg.x * __int_as_float(__builtin_amdgcn_ds_bpermute((ip.x & 63) << 2, wb));
            o.y = xv[c].y + sg.y * __int_as_float(__builtin_amdgcn_ds_bpermute((ip.y & 63) << 2, wb));
            o.z = xv[c].z + sg.z * __int_as_float(__builtin_amdgcn_ds_bpermute((ip.z & 63) << 2, wb));
            o.w = xv[c].w + sg.w * __int_as_float(__builtin_amdgcn_ds_bpermute((ip.w & 63) << 2, wb));
            ((float4*)outr)[c * 64 + lane] = o;
        }

        // ---- Rotate pipeline registers
        if (r + 1 < RPW) {
            #pragma unroll
            for (int c = 0; c < 4; ++c) xv[c] = xn[c];
        }
    }
}

extern "C" void kernel_launch(void* const* d_in, const int* in_sizes, int n_in,
                              void* d_out, int out_size, void* d_ws, size_t ws_size,
                              hipStream_t stream) {
    const float* x        = (const float*)d_in[0];
    const float* gates    = (const float*)d_in[1];
    const float* alpha    = (const float*)d_in[2];
    const float* tau      = (const float*)d_in[3];
    const float* signs    = (const float*)d_in[4];
    const int*   perm     = (const int*)d_in[5];
    const int*   inv_perm = (const int*)d_in[6];
    const int*   tgt      = (const int*)d_in[7];
    float*       out      = (float*)d_out;

    const int rows = 4 * SEQ;                          // BSZ * SEQ
    csa_kernel<<<rows / (WPB * RPW), WPB * 64, 0, stream>>>(
        x, gates, alpha, tau, signs, perm, inv_perm, tgt, out);
}

// Round 6
// 124.213 us; speedup vs baseline: 1.0529x; 1.0529x over previous
//
#include <hip/hip_runtime.h>

#define SEQ 4096
#define DIM 1024
#define MD 64
#define TOPK 16
#define WPB 2                 // waves per block
#define RPW 2                 // rows per wave (ILP: two independent chains)
#define RPB (WPB * RPW)       // 4 rows per block, 16 KB LDS

typedef float nfloat4 __attribute__((ext_vector_type(4)));  // native vec for nt-store

// R3 structure (best so far) + two zero-occupancy-cost fixes:
//  - epilogue reads x from REGISTERS (out = x + signs*w[bin], signs^2==1):
//    deletes all phase-4 ds_read_b128 LDS traffic
//  - nontemporal float4 stores for out (never re-read): keeps L2/L3 for x
// Identities (validated R1-R4):
//   z_m = 1024^-0.5 * H64(s)_m,  s[m] = sum_k (x*signs)[perm[m+64k]]
//   out[d] = x[d] + signs[d] * (1024^-0.5 * H64(zs))[inv_perm[d] & 63]
__global__ __launch_bounds__(WPB * 64) void csa_kernel(
    const float* __restrict__ x,
    const float* __restrict__ gates,
    const float* __restrict__ alpha,
    const float* __restrict__ tau,
    const float* __restrict__ signs,
    const int*   __restrict__ perm,
    const int*   __restrict__ inv_perm,
    const int*   __restrict__ target_idx,
    float*       __restrict__ out)
{
    __shared__ float y[RPB][DIM];

    const int lane = threadIdx.x & 63;
    const int wv   = threadIdx.x >> 6;
    const int r0   = (blockIdx.x * WPB + wv) * RPW;   // first of 2 rows (even)
    const int b    = r0 >> 12;                        // SEQ = 4096; pair shares b

    // ---- Phase 1: coalesced loads; x stays in registers; y = x*signs -> LDS
    float4 xv0[4], xv1[4];
    #pragma unroll
    for (int c = 0; c < 4; ++c) {
        const float4 sg = ((const float4*)signs)[c * 64 + lane];
        xv0[c] = ((const float4*)(x + (size_t)(r0 + 0) * DIM))[c * 64 + lane];
        xv1[c] = ((const float4*)(x + (size_t)(r0 + 1) * DIM))[c * 64 + lane];
        float4 y0, y1;
        y0.x = xv0[c].x * sg.x; y0.y = xv0[c].y * sg.y;
        y0.z = xv0[c].z * sg.z; y0.w = xv0[c].w * sg.w;
        y1.x = xv1[c].x * sg.x; y1.y = xv1[c].y * sg.y;
        y1.z = xv1[c].z * sg.z; y1.w = xv1[c].w * sg.w;
        ((float4*)y[wv * RPW + 0])[c * 64 + lane] = y0;
        ((float4*)y[wv * RPW + 1])[c * 64 + lane] = y1;
    }

    // ---- Phase 2: fold 1024 -> 64 bins; lane m owns bin m; rows share perm
    float s0 = 0.f, s1 = 0.f;
    #pragma unroll
    for (int k = 0; k < 16; ++k) {
        const int p = perm[lane + 64 * k];            // L1-hot, shared
        s0 += y[wv * RPW + 0][p];
        s1 += y[wv * RPW + 1][p];
    }

    // ---- Phase 3a: 64-pt Hadamard, both rows interleaved
    float v0 = s0, v1 = s1;
    #pragma unroll
    for (int bit = 1; bit < MD; bit <<= 1) {
        const float o0 = __shfl_xor(v0, bit, 64);
        const float o1 = __shfl_xor(v1, bit, 64);
        v0 = (lane & bit) ? (o0 - v0) : (v0 + o0);
        v1 = (lane & bit) ? (o1 - v1) : (v1 + o1);
    }

    const int   ti   = target_idx[0];                 // NT == 1
    const float gate = gates[(b + ti) * MD + lane];
    const float tauv = fabsf(tau[b + ti]);
    const float al   = alpha[b + ti];

    const float g0 = gate * v0 * 0.03125f;            // 1024^-0.5
    const float g1 = gate * v1 * 0.03125f;
    const float ag0 = fabsf(g0), ag1 = fabsf(g1);

    // ---- Phase 3b: exact top-16 via bitwise binary search (2 chains);
    // ties -> lowest lane (matches jax.lax.top_k)
    const unsigned ka0 = __float_as_uint(ag0);
    const unsigned ka1 = __float_as_uint(ag1);
    unsigned T0 = 0u, T1 = 0u;
    #pragma unroll
    for (int bit = 30; bit >= 0; --bit) {
        const unsigned c0 = T0 | (1u << bit);
        const unsigned c1 = T1 | (1u << bit);
        if (__popcll(__ballot(ka0 >= c0)) >= TOPK) T0 = c0;
        if (__popcll(__ballot(ka1 >= c1)) >= TOPK) T1 = c1;
    }
    const int ngt0 = __popcll(__ballot(ka0 > T0));
    const int ngt1 = __popcll(__ballot(ka1 > T1));
    const unsigned long long lm = (1ull << lane) - 1ull;
    const int er0 = __popcll(__ballot(ka0 == T0) & lm);
    const int er1 = __popcll(__ballot(ka1 == T1) & lm);
    const bool k0 = (ka0 > T0) || ((ka0 == T0) && (er0 < TOPK - ngt0));
    const bool k1 = (ka1 > T1) || ((ka1 == T1) && (er1 < TOPK - ngt1));

    float zs0 = (k0 && ag0 >= tauv) ? al * g0 : 0.f;
    float zs1 = (k1 && ag1 >= tauv) ? al * g1 : 0.f;

    // ---- Phase 3c: second 64-pt Hadamard, interleaved
    #pragma unroll
    for (int bit = 1; bit < MD; bit <<= 1) {
        const float o0 = __shfl_xor(zs0, bit, 64);
        const float o1 = __shfl_xor(zs1, bit, 64);
        zs0 = (lane & bit) ? (o0 - zs0) : (zs0 + o0);
        zs1 = (lane & bit) ? (o1 - zs1) : (zs1 + o1);
    }
    const int wb0 = __float_as_int(zs0 * 0.03125f);
    const int wb1 = __float_as_int(zs1 * 0.03125f);

    // ---- Phase 4: out = x + signs * w[inv_perm & 63]; x from registers;
    // nontemporal stores (out never re-read)
    nfloat4* out0 = (nfloat4*)(out + (size_t)(r0 + 0) * DIM);
    nfloat4* out1 = (nfloat4*)(out + (size_t)(r0 + 1) * DIM);
    #pragma unroll
    for (int c = 0; c < 4; ++c) {
        const float4 sg = ((const float4*)signs)[c * 64 + lane];
        const int4   ip = ((const int4*)inv_perm)[c * 64 + lane];
        const int a0 = (ip.x & 63) << 2, a1 = (ip.y & 63) << 2;
        const int a2 = (ip.z & 63) << 2, a3 = (ip.w & 63) << 2;

        nfloat4 o0, o1;
        o0.x = xv0[c].x + sg.x * __int_as_float(__builtin_amdgcn_ds_bpermute(a0, wb0));
        o0.y = xv0[c].y + sg.y * __int_as_float(__builtin_amdgcn_ds_bpermute(a1, wb0));
        o0.z = xv0[c].z + sg.z * __int_as_float(__builtin_amdgcn_ds_bpermute(a2, wb0));
        o0.w = xv0[c].w + sg.w * __int_as_float(__builtin_amdgcn_ds_bpermute(a3, wb0));
        o1.x = xv1[c].x + sg.x * __int_as_float(__builtin_amdgcn_ds_bpermute(a0, wb1));
        o1.y = xv1[c].y + sg.y * __int_as_float(__builtin_amdgcn_ds_bpermute(a1, wb1));
        o1.z = xv1[c].z + sg.z * __int_as_float(__builtin_amdgcn_ds_bpermute(a2, wb1));
        o1.w = xv1[c].w + sg.w * __int_as_float(__builtin_amdgcn_ds_bpermute(a3, wb1));

        __builtin_nontemporal_store(o0, &out0[c * 64 + lane]);
        __builtin_nontemporal_store(o1, &out1[c * 64 + lane]);
    }
}

extern "C" void kernel_launch(void* const* d_in, const int* in_sizes, int n_in,
                              void* d_out, int out_size, void* d_ws, size_t ws_size,
                              hipStream_t stream) {
    const float* x        = (const float*)d_in[0];
    const float* gates    = (const float*)d_in[1];
    const float* alpha    = (const float*)d_in[2];
    const float* tau      = (const float*)d_in[3];
    const float* signs    = (const float*)d_in[4];
    const int*   perm     = (const int*)d_in[5];
    const int*   inv_perm = (const int*)d_in[6];
    const int*   tgt      = (const int*)d_in[7];
    float*       out      = (float*)d_out;

    const int rows = 4 * SEQ;                         // BSZ * SEQ
    csa_kernel<<<rows / RPB, WPB * 64, 0, stream>>>(x, gates, alpha, tau, signs,
                                                    perm, inv_perm, tgt, out);
}

// Round 7
// 123.566 us; speedup vs baseline: 1.0584x; 1.0052x over previous
//
#include <hip/hip_runtime.h>

#define SEQ 4096
#define DIM 1024
#define MD 64
#define TOPK 16
#define WPB 2                 // waves per block
#define RPW 2                 // rows per wave (ILP: two independent chains)
#define RPB (WPB * RPW)       // 4 rows per block, 16 KB LDS

typedef float nfloat4 __attribute__((ext_vector_type(4)));  // native vec for nt-store

// R6 + zero-bpermute epilogue. Key identity: processing the epilogue in perm
// order means element d = perm[L + 64k] has bin inv_perm[d]&63 == L, so lane L
// needs only ITS OWN w[L] — no cross-lane traffic. The gathered y values from
// the fold phase are reused from registers; t = y + w is scattered over the
// staging buffer and read back linearly for coalesced nt stores.
//   z_m = 1024^-0.5 * H64(s)_m,  s[m] = sum_k (x*signs)[perm[m+64k]]
//   out[d] = signs[d] * ( y[d] + (1024^-0.5 * H64(zs))[inv_perm[d] & 63] )
__global__ __launch_bounds__(WPB * 64) void csa_kernel(
    const float* __restrict__ x,
    const float* __restrict__ gates,
    const float* __restrict__ alpha,
    const float* __restrict__ tau,
    const float* __restrict__ signs,
    const int*   __restrict__ perm,
    const int*   __restrict__ inv_perm,
    const int*   __restrict__ target_idx,
    float*       __restrict__ out)
{
    __shared__ float y[RPB][DIM];

    const int lane = threadIdx.x & 63;
    const int wv   = threadIdx.x >> 6;
    const int r0   = (blockIdx.x * WPB + wv) * RPW;   // first of 2 rows (even)
    const int b    = r0 >> 12;                        // SEQ = 4096; pair shares b

    float* y0 = y[wv * RPW + 0];
    float* y1 = y[wv * RPW + 1];

    // ---- Phase 1: coalesced loads; y = x*signs -> LDS (x regs then dead)
    #pragma unroll
    for (int c = 0; c < 4; ++c) {
        const float4 sg = ((const float4*)signs)[c * 64 + lane];
        const float4 xa = ((const float4*)(x + (size_t)(r0 + 0) * DIM))[c * 64 + lane];
        const float4 xb = ((const float4*)(x + (size_t)(r0 + 1) * DIM))[c * 64 + lane];
        float4 a, bq;
        a.x  = xa.x * sg.x; a.y  = xa.y * sg.y; a.z  = xa.z * sg.z; a.w  = xa.w * sg.w;
        bq.x = xb.x * sg.x; bq.y = xb.y * sg.y; bq.z = xb.z * sg.z; bq.w = xb.w * sg.w;
        ((float4*)y0)[c * 64 + lane] = a;
        ((float4*)y1)[c * 64 + lane] = bq;
    }

    // ---- Phase 2: fold 1024 -> 64 bins; keep gathered values + addresses
    int   pk[16];
    float ya[16], yb[16];
    float s0 = 0.f, s1 = 0.f;
    #pragma unroll
    for (int k = 0; k < 16; ++k) {
        pk[k] = perm[lane + 64 * k];                  // L1-hot, shared by rows
        ya[k] = y0[pk[k]];
        yb[k] = y1[pk[k]];
        s0 += ya[k];
        s1 += yb[k];
    }

    // ---- Phase 3a: 64-pt Hadamard, both rows interleaved
    float v0 = s0, v1 = s1;
    #pragma unroll
    for (int bit = 1; bit < MD; bit <<= 1) {
        const float o0 = __shfl_xor(v0, bit, 64);
        const float o1 = __shfl_xor(v1, bit, 64);
        v0 = (lane & bit) ? (o0 - v0) : (v0 + o0);
        v1 = (lane & bit) ? (o1 - v1) : (v1 + o1);
    }

    const int   ti   = target_idx[0];                 // NT == 1
    const float gate = gates[(b + ti) * MD + lane];
    const float tauv = fabsf(tau[b + ti]);
    const float al   = alpha[b + ti];

    const float g0 = gate * v0 * 0.03125f;            // 1024^-0.5
    const float g1 = gate * v1 * 0.03125f;
    const float ag0 = fabsf(g0), ag1 = fabsf(g1);

    // ---- Phase 3b: exact top-16 via bitwise binary search (2 chains);
    // ties -> lowest lane (matches jax.lax.top_k)
    const unsigned ka0 = __float_as_uint(ag0);
    const unsigned ka1 = __float_as_uint(ag1);
    unsigned T0 = 0u, T1 = 0u;
    #pragma unroll
    for (int bit = 30; bit >= 0; --bit) {
        const unsigned c0 = T0 | (1u << bit);
        const unsigned c1 = T1 | (1u << bit);
        if (__popcll(__ballot(ka0 >= c0)) >= TOPK) T0 = c0;
        if (__popcll(__ballot(ka1 >= c1)) >= TOPK) T1 = c1;
    }
    const int ngt0 = __popcll(__ballot(ka0 > T0));
    const int ngt1 = __popcll(__ballot(ka1 > T1));
    const unsigned long long lm = (1ull << lane) - 1ull;
    const int er0 = __popcll(__ballot(ka0 == T0) & lm);
    const int er1 = __popcll(__ballot(ka1 == T1) & lm);
    const bool k0 = (ka0 > T0) || ((ka0 == T0) && (er0 < TOPK - ngt0));
    const bool k1 = (ka1 > T1) || ((ka1 == T1) && (er1 < TOPK - ngt1));

    float zs0 = (k0 && ag0 >= tauv) ? al * g0 : 0.f;
    float zs1 = (k1 && ag1 >= tauv) ? al * g1 : 0.f;

    // ---- Phase 3c: second 64-pt Hadamard, interleaved
    #pragma unroll
    for (int bit = 1; bit < MD; bit <<= 1) {
        const float o0 = __shfl_xor(zs0, bit, 64);
        const float o1 = __shfl_xor(zs1, bit, 64);
        zs0 = (lane & bit) ? (o0 - zs0) : (zs0 + o0);
        zs1 = (lane & bit) ? (o1 - zs1) : (zs1 + o1);
    }
    const float w0 = zs0 * 0.03125f;                  // lane's own bin value
    const float w1 = zs1 * 0.03125f;

    // ---- Phase 4a: scatter t = y + w over the staging buffer (perm order:
    // element perm[lane+64k] has bin == lane, so w needs no cross-lane move)
    #pragma unroll
    for (int k = 0; k < 16; ++k) {
        y0[pk[k]] = ya[k] + w0;
        y1[pk[k]] = yb[k] + w1;
    }

    // ---- Phase 4b: linear readback, out = signs * t, nontemporal store
    nfloat4* out0 = (nfloat4*)(out + (size_t)(r0 + 0) * DIM);
    nfloat4* out1 = (nfloat4*)(out + (size_t)(r0 + 1) * DIM);
    #pragma unroll
    for (int c = 0; c < 4; ++c) {
        const float4 sg = ((const float4*)signs)[c * 64 + lane];
        const float4 t0 = ((const float4*)y0)[c * 64 + lane];
        const float4 t1 = ((const float4*)y1)[c * 64 + lane];
        nfloat4 o0, o1;
        o0.x = sg.x * t0.x; o0.y = sg.y * t0.y; o0.z = sg.z * t0.z; o0.w = sg.w * t0.w;
        o1.x = sg.x * t1.x; o1.y = sg.y * t1.y; o1.z = sg.z * t1.z; o1.w = sg.w * t1.w;
        __builtin_nontemporal_store(o0, &out0[c * 64 + lane]);
        __builtin_nontemporal_store(o1, &out1[c * 64 + lane]);
    }
}

extern "C" void kernel_launch(void* const* d_in, const int* in_sizes, int n_in,
                              void* d_out, int out_size, void* d_ws, size_t ws_size,
                              hipStream_t stream) {
    const float* x        = (const float*)d_in[0];
    const float* gates    = (const float*)d_in[1];
    const float* alpha    = (const float*)d_in[2];
    const float* tau      = (const float*)d_in[3];
    const float* signs    = (const float*)d_in[4];
    const int*   perm     = (const int*)d_in[5];
    const int*   inv_perm = (const int*)d_in[6];   // unused now, kept for signature clarity
    const int*   tgt      = (const int*)d_in[7];
    float*       out      = (float*)d_out;

    const int rows = 4 * SEQ;                         // BSZ * SEQ
    csa_kernel<<<rows / RPB, WPB * 64, 0, stream>>>(x, gates, alpha, tau, signs,
                                                    perm, inv_perm, tgt, out);
}